// Round 9
// baseline (63.312 us; speedup 1.0000x reference)
//
#include <hip/hip_runtime.h>

// ---------- types ----------
using f32x4  = __attribute__((ext_vector_type(4))) float;
using bf16x8 = __attribute__((ext_vector_type(8))) short;   // 8 bf16 in 4 VGPRs

__device__ __forceinline__ unsigned short f2bf(float f) {
    union { float f; unsigned int u; } v; v.f = f;
    unsigned int r = v.u + 0x7fffu + ((v.u >> 16) & 1u);  // RNE
    return (unsigned short)(r >> 16);
}

__device__ __forceinline__ float bf2f(unsigned short u) {
    union { unsigned int u; float f; } v; v.u = ((unsigned int)u) << 16;
    return v.f;
}

// ---------- transpose D [16][256c][256q] f32 -> Dt [16][256q][256c] bf16; zero stats ----------
__global__ __launch_bounds__(256) void transposeD(
    const float* __restrict__ x, unsigned short* __restrict__ y, float* __restrict__ stats) {
    __shared__ float tile[32][33];
    int b  = blockIdx.z;
    int p0 = blockIdx.x * 32;      // q tile
    int c0 = blockIdx.y * 32;      // c tile
    const float* xb = x + (size_t)b * 256 * 256;
    unsigned short* yb = y + (size_t)b * 256 * 256;
    int tx = threadIdx.x, ty = threadIdx.y;
    #pragma unroll
    for (int i = 0; i < 32; i += 8)
        tile[ty + i][tx] = xb[(size_t)(c0 + ty + i) * 256 + (p0 + tx)];
    __syncthreads();
    int tid = ty * 32 + tx;
    #pragma unroll
    for (int k = 0; k < 2; ++k) {
        int wi = tid * 2 + k;          // 0..511
        int pl = wi >> 4;              // local q row
        int cp = wi & 15;              // c-pair
        unsigned short lo = f2bf(tile[2 * cp][pl]);
        unsigned short hi = f2bf(tile[2 * cp + 1][pl]);
        unsigned int packed = (unsigned int)lo | ((unsigned int)hi << 16);
        *reinterpret_cast<unsigned int*>(&yb[(size_t)(p0 + pl) * 256 + (c0 + 2 * cp)]) = packed;
    }
    if (blockIdx.x == 0 && blockIdx.y == 0 && blockIdx.z == 0 && tid == 0) {
        stats[0] = 0.f;
        stats[1] = 0.f;
    }
}

// ---------- producer/consumer pipelined conv ----------
// Grid 256 = (b<<4)|rq; block 512 threads: waves 0-3 compute, waves 4-7 stage.
// Each block processes 4 r-tiles with double-buffered 32KB LDS A-images.
// A image layout: byte(p,c) = p*512 + (((c>>3)^(p&15)^(p>>4))<<4) + (c&7)*2
// gt overlays the consumed A buffer, shifted-column: gt[q*64 + ((p - (q&15))&63)] = G[p][q]
// Raw s_barrier + lgkmcnt-only waits: stager global loads stay in flight across barriers.
#define LOADREGS(RR) do { \
    const float* Sp_ = Sb + (size_t)(RR) * 64 + 4 * px; \
    _Pragma("unroll") for (int rho = 0; rho < 4; ++rho) { \
        int c0_ = rho * 64 + 4 * cq; \
        _Pragma("unroll") for (int j = 0; j < 4; ++j) \
            v[rho][j] = *reinterpret_cast<const f32x4*>(Sp_ + (size_t)(c0_ + j) * 4096); \
    } } while (0)

#define WRITEBUF(BUF) do { \
    _Pragma("unroll") for (int rho = 0; rho < 4; ++rho) { \
        int slot_ = 8 * rho + (cq >> 1); \
        int half_ = cq & 1; \
        _Pragma("unroll") for (int e = 0; e < 4; ++e) { \
            int p_ = 4 * px + e; \
            int swz_ = (p_ & 15) ^ (p_ >> 4); \
            ushort4 o_; \
            o_.x = f2bf(v[rho][0][e]); o_.y = f2bf(v[rho][1][e]); \
            o_.z = f2bf(v[rho][2][e]); o_.w = f2bf(v[rho][3][e]); \
            *reinterpret_cast<ushort4*>((BUF) + p_ * 512 + ((slot_ ^ swz_) << 4) + half_ * 8) = o_; \
        } } } while (0)

#define BARRIER() do { \
    asm volatile("s_waitcnt lgkmcnt(0)" ::: "memory"); \
    __builtin_amdgcn_s_barrier(); } while (0)

__global__ __launch_bounds__(512, 2) void conv_pipe(
    const float* __restrict__ S,             // [16][256][64][64] f32
    const unsigned short* __restrict__ Dt,   // [16][256q][256c] bf16
    float* __restrict__ P) {                 // [16][64][16][52] f32 partials
    __shared__ __align__(16) char lds[2 * 32768];

    int b  = blockIdx.x >> 4;
    int rq = blockIdx.x & 15;
    int r0 = rq * 4;
    int tid = threadIdx.x;
    int wv  = tid >> 6;
    bool stager = (wv >= 4);

    // stager addressing
    int t2 = tid & 255;
    int px = t2 & 15, cq = t2 >> 4;
    const float* Sb = S + (size_t)b * 256 * 4096;

    // computer addressing
    int w = wv & 3;
    int lane = tid & 63;
    int m = lane & 15, kg = lane >> 4;
    const unsigned short* Db = Dt + (size_t)(b * 256 + 64 * w) * 256;

    f32x4 v[4][4];

    // ---- prologue: stage tile0 -> buf0, issue tile1 loads ----
    if (stager) {
        LOADREGS(r0);
        WRITEBUF(lds);
        LOADREGS(r0 + 1);
    }
    BARRIER();

    for (int t = 0; t < 4; ++t) {
        char* bufc = lds + ((t & 1) << 15);
        char* bufn = lds + (((t + 1) & 1) << 15);

        f32x4 acc[4][4];
        if (stager) {
            if (t < 3) WRITEBUF(bufn);       // waits vmcnt on v (loads issued last iter)
            if (t < 2) LOADREGS(r0 + t + 2); // issue next-next tile; in flight across barriers
        } else {
            #pragma unroll
            for (int i = 0; i < 4; ++i)
                #pragma unroll
                for (int j = 0; j < 4; ++j)
                    acc[i][j] = f32x4{0.f, 0.f, 0.f, 0.f};
            bf16x8 bcur[4];
            #pragma unroll
            for (int n = 0; n < 4; ++n)
                bcur[n] = *reinterpret_cast<const bf16x8*>(Db + (size_t)(16 * n + m) * 256 + kg * 8);
            #pragma unroll
            for (int st = 0; st < 8; ++st) {
                bf16x8 af[4];
                #pragma unroll
                for (int pa = 0; pa < 4; ++pa) {
                    int p = 16 * pa + m;
                    int slot = (4 * st + kg) ^ m ^ pa;   // (c>>3)^(p&15)^(p>>4)
                    af[pa] = *reinterpret_cast<const bf16x8*>(bufc + p * 512 + (slot << 4));
                }
                #pragma unroll
                for (int pa = 0; pa < 4; ++pa)
                    #pragma unroll
                    for (int n = 0; n < 4; ++n)
                        acc[pa][n] = __builtin_amdgcn_mfma_f32_16x16x32_bf16(af[pa], bcur[n], acc[pa][n], 0, 0, 0);
                if (st < 7) {
                    #pragma unroll
                    for (int n = 0; n < 4; ++n)
                        bcur[n] = *reinterpret_cast<const bf16x8*>(
                            Db + (size_t)(16 * n + m) * 256 + (st + 1) * 32 + kg * 8);
                }
            }
        }
        BARRIER();   // B1: A(t+1) written; all GEMM reads of bufc done

        unsigned short* gt = (unsigned short*)bufc;
        if (!stager) {
            // dump shifted-column gt into the consumed buffer
            #pragma unroll
            for (int pa = 0; pa < 4; ++pa)
                #pragma unroll
                for (int n = 0; n < 4; ++n) {
                    int q = 64 * w + 16 * n + m;
                    #pragma unroll
                    for (int e = 0; e < 4; ++e) {
                        int p = 16 * pa + 4 * kg + e;
                        gt[q * 64 + ((p - m) & 63)] = f2bf(acc[pa][n][e]);
                    }
                }
        }
        BARRIER();   // B2: gt complete

        // ---- gather (all 8 waves): P[b][r][i][x] = sum_j gt[(16i+j)*64 + x] ----
        {
            int r = r0 + t;
            int ilo = (r > 48) ? (r - 48) : 0;
            int ihi = (r < 15) ? r : 15;
            int total = (ihi - ilo + 1) * 49;
            for (int o = tid; o < total; o += 512) {
                int i = ilo + o / 49;
                int x = o % 49;
                float s = 0.f;
                int qb = 16 * i;
                #pragma unroll
                for (int j = 0; j < 16; ++j)
                    s += bf2f(gt[(qb + j) * 64 + x]);
                P[((size_t)((b * 64 + r) * 16 + i)) * 52 + x] = s;
            }
        }
        BARRIER();   // B3: gather reads done before next overwrite of gt/bufs
    }
}

// ---------- reduce partials + global stats: mm[b][y][x] = sum_i P[b][y+i][i][x] ----------
__global__ __launch_bounds__(256) void reduce_kernel(
    const float* __restrict__ P, float* __restrict__ mm, float* __restrict__ stats) {
    int idx = blockIdx.x * 256 + threadIdx.x;
    float s = 0.f;
    if (idx < 38416) {
        int b  = idx / 2401;
        int yx = idx % 2401;
        int y  = yx / 49;
        int x  = yx % 49;
        #pragma unroll
        for (int i = 0; i < 16; ++i)
            s += P[((size_t)((b * 64 + y + i) * 16 + i)) * 52 + x];
        mm[idx] = s;
    }
    __shared__ float rs[256];
    __shared__ float rq[256];
    int tid = threadIdx.x;
    rs[tid] = (idx < 38416) ? s : 0.f;
    rq[tid] = (idx < 38416) ? s * s : 0.f;
    __syncthreads();
    for (int st = 128; st > 0; st >>= 1) {
        if (tid < st) { rs[tid] += rs[tid + st]; rq[tid] += rq[tid + st]; }
        __syncthreads();
    }
    if (tid == 0) {
        atomicAdd(&stats[0], rs[0]);
        atomicAdd(&stats[1], rq[0]);
    }
}

// ---------- fallback naive conv (tiny ws) ----------
__global__ __launch_bounds__(256) void conv_naive(
    const float* __restrict__ S, const float* __restrict__ D, float* __restrict__ mm) {
    int blk = blockIdx.x;            // b*2401 + y*49 + x
    int b = blk / 2401;
    int yx = blk % 2401;
    int y = yx / 49, x = yx % 49;
    int c = threadIdx.x;
    const float* Sp = S + (((size_t)b * 256 + c) * 64 + y) * 64 + x;
    const float* Dp = D + ((size_t)b * 256 + c) * 256;
    float s = 0.f;
    #pragma unroll
    for (int i = 0; i < 16; ++i)
        #pragma unroll 4
        for (int j = 0; j < 16; ++j)
            s += Sp[i * 64 + j] * Dp[i * 16 + j];
    __shared__ float red[256];
    red[c] = s;
    __syncthreads();
    for (int st = 128; st > 0; st >>= 1) {
        if (c < st) red[c] += red[c + st];
        __syncthreads();
    }
    if (c == 0) mm[blk] = red[0];
}

// ---------- fallback stats: raw sums ----------
__global__ __launch_bounds__(1024) void stats_kernel(
    const float* __restrict__ mm, float* __restrict__ stats) {
    __shared__ float ssum[1024];
    __shared__ float ssq[1024];
    int tid = threadIdx.x;
    float s = 0.f, q = 0.f;
    for (int i = tid; i < 38416; i += 1024) {
        float v = mm[i];
        s += v; q += v * v;
    }
    ssum[tid] = s; ssq[tid] = q;
    __syncthreads();
    for (int st = 512; st > 0; st >>= 1) {
        if (tid < st) { ssum[tid] += ssum[tid + st]; ssq[tid] += ssq[tid + st]; }
        __syncthreads();
    }
    if (tid == 0) {
        stats[0] = ssum[0];
        stats[1] = ssq[0];
    }
}

// ---------- normalize + bilinear 49x49 -> 256x256 (float4 stores; stats are raw sums) ----------
__global__ __launch_bounds__(256) void bilinear_kernel(
    const float* __restrict__ mm, const float* __restrict__ stats,
    const float* __restrict__ gamma, const float* __restrict__ beta,
    float* __restrict__ out) {
    int idx4 = blockIdx.x * 256 + threadIdx.x;   // 262144 quads
    int b   = idx4 >> 14;
    int rem = idx4 & 16383;
    int oy  = rem >> 6;
    int ox0 = (rem & 63) << 2;
    const float scale = 49.0f / 256.0f;
    float cy = fminf(fmaxf((oy + 0.5f) * scale - 0.5f, 0.0f), 48.0f);
    int y0 = (int)cy; int y1 = min(y0 + 1, 48); float wy = cy - (float)y0;
    const float* mb = mm + (size_t)b * 2401;
    const float invN = 1.0f / 38416.0f;
    float mean = stats[0] * invN;
    float var  = stats[1] * invN - mean * mean;
    float rstd = rsqrtf(var + 1e-5f);
    float g = gamma[0], be = beta[0];
    f32x4 res;
    #pragma unroll
    for (int e = 0; e < 4; ++e) {
        int ox = ox0 + e;
        float cx = fminf(fmaxf((ox + 0.5f) * scale - 0.5f, 0.0f), 48.0f);
        int x0 = (int)cx; int x1 = min(x0 + 1, 48); float wx = cx - (float)x0;
        float v00 = mb[y0 * 49 + x0];
        float v01 = mb[y0 * 49 + x1];
        float v10 = mb[y1 * 49 + x0];
        float v11 = mb[y1 * 49 + x1];
        float r0 = v00 * (1.f - wy) + v10 * wy;
        float r1 = v01 * (1.f - wy) + v11 * wy;
        float vv = r0 * (1.f - wx) + r1 * wx;
        res[e] = (vv - mean) * rstd * g + be;
    }
    *reinterpret_cast<f32x4*>(out + ((size_t)b << 16) + (oy << 8) + ox0) = res;
}

extern "C" void kernel_launch(void* const* d_in, const int* in_sizes, int n_in,
                              void* d_out, int out_size, void* d_ws, size_t ws_size,
                              hipStream_t stream) {
    const float* S     = (const float*)d_in[0];   // (16,256,64,64)
    const float* D     = (const float*)d_in[1];   // (16,256,16,16)
    const float* gamma = (const float*)d_in[2];   // (1,)
    const float* beta  = (const float*)d_in[3];   // (1,)
    float* out = (float*)d_out;                   // (16,1,256,256)

    char* ws = (char*)d_ws;
    const size_t sizeDt = (size_t)16 * 256 * 256 * 2;        // 2,097,152
    const size_t sizeMm = (size_t)38416 * 4;                 //   153,664
    const size_t sizeP  = (size_t)16 * 64 * 16 * 52 * 4;     // 3,407,872
    const size_t offDt = 0;
    const size_t offMm = offDt + sizeDt;
    const size_t offStats = offMm + sizeMm;
    const size_t offP = (offStats + 2 * sizeof(float) + 255) & ~(size_t)255;
    const size_t needFast = offP + sizeP;

    bool fast = (ws_size >= needFast);
    float* mm;
    float* stats;
    if (fast) {
        mm    = (float*)(ws + offMm);
        stats = (float*)(ws + offStats);
    } else {
        mm    = (float*)ws;
        stats = (float*)(ws + sizeMm);
    }

    if (fast) {
        unsigned short* Dt = (unsigned short*)(ws + offDt);
        float* P = (float*)(ws + offP);
        transposeD<<<dim3(8, 8, 16), dim3(32, 8), 0, stream>>>(D, Dt, stats);
        conv_pipe<<<256, 512, 0, stream>>>(S, Dt, P);
        reduce_kernel<<<151, 256, 0, stream>>>(P, mm, stats);
    } else {
        conv_naive<<<16 * 2401, 256, 0, stream>>>(S, D, mm);
        stats_kernel<<<1, 1024, 0, stream>>>(mm, stats);
    }
    bilinear_kernel<<<1024, 256, 0, stream>>>(mm, stats, gamma, beta, out);
}